// Round 9
// baseline (38.980 us; speedup 1.0000x reference)
//
#include <hip/hip_runtime.h>
#include <stdint.h>

// DistMatchLayer via spatial bucketing, round 9.
// Change vs round 8: NO cross-lane reduction inside the chunk loop.
//  - Per-lane persistent top-5 lists across chunks; ONE butterfly merge per
//    row at the end (round 8 did a 30-dependent-shfl extract PER CHUNK --
//    that serial latency chain was the cost, not the op count).
//  - Early exit via candidate COUNT, not the 5th-best key: the constexpr
//    offset table is SHELL-ALIGNED (chunks padded so no d2 shell straddles a
//    boundary; canStop bitmask marks strict-d2-increase boundaries). At a
//    canStop boundary with cum >= 5 scanned slot-candidates, the 5 best
//    scanned keys provably beat every unscanned key (strict d2 separation,
//    ties cannot straddle). Count = 8 ballots + popcount (scalar pipe, no
//    shfl). Hi-slot/overflow candidates are NOT counted (undercount only
//    delays the stop -- always safe); they ARE inserted/folded for exactness.
//  - Overflow fold + (g4>>13)>kDMax brute fallback unchanged from round 8.
// Exact & stable: full keys (d2<<13)|j, order-independent top-5-of-union.

namespace {
constexpr int kB = 4;
constexpr int kNa = 8192;
constexpr int kNb = 8192;
constexpr int kC = 64;

constexpr int kRad = 8;                 // offsets |d| <= 8, d2 <= 64
constexpr int kDMax = 64;
constexpr int kGrid = 48;               // 32 + 2*8 padded grid
constexpr int kGrid2 = kGrid * kGrid;   // 2304
constexpr int kGrid3 = kGrid2 * kGrid;  // 110592
constexpr int kOff = kRad * kGrid2 + kRad * kGrid + kRad;  // 19208

constexpr int kChunkSz = 128;
constexpr int kMaxChunks = 48;
constexpr int kTabCap = kMaxChunks * kChunkSz;   // 6144 (ball(8) = 2109 + pads)

constexpr int kOvfCap = 256;

// ws layout (u32 words) -- same as round 8
constexpr size_t kCntOff    = 0;                                     // [442368]
constexpr size_t kOvfCntOff = 442368;                                // [4]
constexpr size_t kOvfIdxOff = 442372;                                // [1024]
constexpr size_t kSlotLoOff = 443396;                                // 16B-aligned
constexpr size_t kSlotHiOff = kSlotLoOff + (size_t)kB * kGrid3 * 4;
constexpr size_t kWsWords   = kSlotHiOff + (size_t)kB * kGrid3 * 4;
constexpr size_t kWsBytes   = kWsWords * 4ull;                       // ~15.9 MB

constexpr int kZeroVecEnd = (int)((kOvfCntOff + 4) / 4);
constexpr int kFFVecBeg   = (int)(kSlotLoOff / 4);
constexpr int kFFVecEnd   = (int)(kSlotHiOff / 4);
constexpr int kClrBlocks  = (kFFVecEnd + 255) / 256;

struct Tab {
    uint32_t e[kTabCap];
    unsigned long long canStop;
    int nChunks;
};
constexpr Tab buildTab() {
    Tab t{};
    for (int i = 0; i < kTabCap; ++i) t.e[i] = 0x7FFFFFFFu;  // sentinel
    t.canStop = 0;
    // shell sizes
    int cnt[kDMax + 1] = {};
    for (int dx = -kRad; dx <= kRad; ++dx)
        for (int dy = -kRad; dy <= kRad; ++dy)
            for (int dz = -kRad; dz <= kRad; ++dz) {
                const int d2 = dx * dx + dy * dy + dz * dz;
                if (d2 <= kDMax) cnt[d2]++;
            }
    // shell-aligned packing: pad to chunk boundary when a shell doesn't fit
    int pos[kDMax + 1] = {};
    int fill = 0;
    for (int d = 0; d <= kDMax; ++d) {
        if (cnt[d] == 0) { pos[d] = -1; continue; }
        const int room = kChunkSz - (fill % kChunkSz);
        if (room < cnt[d] && room != kChunkSz) fill += room;
        pos[d] = fill;
        fill += cnt[d];
    }
    t.nChunks = (fill + kChunkSz - 1) / kChunkSz;
    for (int dx = -kRad; dx <= kRad; ++dx)
        for (int dy = -kRad; dy <= kRad; ++dy)
            for (int dz = -kRad; dz <= kRad; ++dz) {
                const int d2 = dx * dx + dy * dy + dz * dz;
                if (d2 <= kDMax) {
                    const int sd = dx * kGrid2 + dy * kGrid + dz + kOff;
                    t.e[pos[d2]++] = ((uint32_t)d2 << 18) | (uint32_t)sd;
                }
            }
    // canStop[c]: min real d2 after chunk c is STRICTLY > max real d2 up to c
    for (int c = 0; c < t.nChunks; ++c) {
        int lastReal = -1;
        for (int i = (c + 1) * kChunkSz - 1; i >= 0; --i) {
            const unsigned d = t.e[i] >> 18;
            if (d <= (unsigned)kDMax) { lastReal = (int)d; break; }
        }
        int nextReal = kDMax + 1;
        for (int i = (c + 1) * kChunkSz; i < kTabCap; ++i) {
            const unsigned d = t.e[i] >> 18;
            if (d <= (unsigned)kDMax) { nextReal = (int)d; break; }
        }
        if (nextReal > lastReal) t.canStop |= (1ull << c);
    }
    return t;
}
__device__ constexpr Tab kTab = buildTab();          // ~24 KB .rodata
constexpr int kNChunks = buildTab().nChunks;
constexpr unsigned long long kCanStop = buildTab().canStop;
}  // namespace

__device__ __forceinline__ uint32_t umin_(uint32_t a, uint32_t b) { return a < b ? a : b; }
__device__ __forceinline__ uint32_t umax_(uint32_t a, uint32_t b) { return a > b ? a : b; }

#define INSERT5(T0, T1, T2, T3, T4, KEY) do {                 \
    const uint32_t m0_ = umax_(T0, KEY); T0 = umin_(T0, KEY); \
    const uint32_t m1_ = umax_(T1, m0_); T1 = umin_(T1, m0_); \
    const uint32_t m2_ = umax_(T2, m1_); T2 = umin_(T2, m1_); \
    const uint32_t m3_ = umax_(T3, m2_); T3 = umin_(T3, m2_); \
    T4 = umin_(T4, m3_); } while (0)

__device__ __forceinline__ void merge5_(uint32_t& t0, uint32_t& t1, uint32_t& t2,
                                        uint32_t& t3, uint32_t& t4,
                                        uint32_t b0, uint32_t b1, uint32_t b2,
                                        uint32_t b3, uint32_t b4) {
    const uint32_t c0 = umin_(t0, b0);
    const uint32_t c1 = umin_(umin_(umax_(t0, b0), t1), b1);
    const uint32_t c2 = umin_(umin_(umax_(t0, b1), umax_(t1, b0)), umin_(t2, b2));
    const uint32_t c3 = umin_(umin_(umax_(t0, b2), umax_(t1, b1)),
                              umin_(umax_(t2, b0), umin_(t3, b3)));
    const uint32_t c4 = umin_(umin_(umax_(t0, b3), umax_(t1, b2)),
                              umin_(umin_(umax_(t2, b1), umax_(t3, b0)),
                                    umin_(t4, b4)));
    t0 = c0; t1 = c1; t2 = c2; t3 = c3; t4 = c4;
}

// butterfly: all 64 lanes end with the wave-global sorted top-5
__device__ __forceinline__ void waveMerge5_(uint32_t& t0, uint32_t& t1, uint32_t& t2,
                                            uint32_t& t3, uint32_t& t4) {
    #pragma unroll
    for (int s = 1; s < 64; s <<= 1) {
        const uint32_t b0 = (uint32_t)__shfl_xor((int)t0, s);
        const uint32_t b1 = (uint32_t)__shfl_xor((int)t1, s);
        const uint32_t b2 = (uint32_t)__shfl_xor((int)t2, s);
        const uint32_t b3 = (uint32_t)__shfl_xor((int)t3, s);
        const uint32_t b4 = (uint32_t)__shfl_xor((int)t4, s);
        merge5_(t0, t1, t2, t3, t4, b0, b1, b2, b3, b4);
    }
}

// ---------------- clear + scatter ----------------

__global__ __launch_bounds__(256)
void k_clear(uint4* __restrict__ ws) {
    const int i = blockIdx.x * 256 + threadIdx.x;
    if (i < kZeroVecEnd) ws[i] = uint4{0u, 0u, 0u, 0u};
    else if (i >= kFFVecBeg && i < kFFVecEnd) ws[i] = uint4{~0u, ~0u, ~0u, ~0u};
}

__global__ void k_scatter(const int* __restrict__ coords_b,
                          uint32_t* __restrict__ cnt,
                          uint32_t* __restrict__ slotLo,
                          uint32_t* __restrict__ slotHi,
                          uint32_t* __restrict__ ovfCnt,
                          uint32_t* __restrict__ ovfIdx) {
    const int i = blockIdx.x * blockDim.x + threadIdx.x;
    if (i >= kB * kNb) return;
    const int b = i >> 13;
    const int j = i & (kNb - 1);
    const int* p = coords_b + (size_t)i * 3;
    const int cell = b * kGrid3
                   + (p[0] + kRad) * kGrid2 + (p[1] + kRad) * kGrid + (p[2] + kRad);
    const uint32_t pos = atomicAdd(&cnt[cell], 1u);
    if (pos < 4u) {
        slotLo[(size_t)cell * 4 + pos] = (uint32_t)j;
    } else if (pos < 8u) {
        slotHi[(size_t)cell * 4 + (pos - 4u)] = (uint32_t)j;
    } else {
        const uint32_t op = atomicAdd(&ovfCnt[b], 1u);
        if (op < (uint32_t)kOvfCap) ovfIdx[b * kOvfCap + op] = (uint32_t)j;
    }
}

// ---------------- main kernel: wave-per-row shell search ----------------

__global__ __launch_bounds__(512, 8)
void dist_match_bucket(const int* __restrict__ coords_a,
                       const int* __restrict__ coords_b,
                       const float* __restrict__ feat_a,
                       const float* __restrict__ feat_b,
                       const uint32_t* __restrict__ cnt,
                       const uint32_t* __restrict__ slotLo,
                       const uint32_t* __restrict__ slotHi,
                       const uint32_t* __restrict__ ovfCnt,
                       const uint32_t* __restrict__ ovfIdx,
                       float* __restrict__ out)
{
    const int b = blockIdx.x >> 10;                // 1024 blocks/batch
    const int rowBase = (blockIdx.x & 1023) * 8;
    const int lane = threadIdx.x & 63;
    const int wave = threadIdx.x >> 6;
    const int row = rowBase + wave;

    const int* ca = coords_a + ((size_t)b * kNa + row) * 3;
    const int ax = ca[0], ay = ca[1], az = ca[2];
    const int aCell = (ax + kRad) * kGrid2 + (ay + kRad) * kGrid + (az + kRad);
    const int base = b * kGrid3 + aCell - kOff;

    // per-lane persistent top-5 over all scanned chunks (no cross-lane ops
    // in the loop; ONE butterfly after the loop)
    uint32_t t0 = 0xFFFFFFFFu, t1 = t0, t2 = t0, t3 = t0, t4 = t0;
    int cum = 0;

    for (int c = 0; c < kNChunks; ++c) {
        const uint32_t e0 = kTab.e[c * kChunkSz + lane];
        const uint32_t e1 = kTab.e[c * kChunkSz + 64 + lane];
        const uint32_t d20 = e0 >> 18, d21 = e1 >> 18;
        const int cell0 = base + (int)(e0 & 0x3FFFFu);
        const int cell1 = base + (int)(e1 & 0x3FFFFu);
        uint4 s0 = uint4{~0u, ~0u, ~0u, ~0u};
        uint4 s1 = uint4{~0u, ~0u, ~0u, ~0u};
        if (d20 <= (uint32_t)kDMax)
            s0 = *reinterpret_cast<const uint4*>(slotLo + (size_t)cell0 * 4);
        if (d21 <= (uint32_t)kDMax)
            s1 = *reinterpret_cast<const uint4*>(slotLo + (size_t)cell1 * 4);

        const uint32_t kb0 = d20 << 13, kb1 = d21 << 13;
        INSERT5(t0, t1, t2, t3, t4, kb0 | s0.x);
        INSERT5(t0, t1, t2, t3, t4, kb0 | s0.y);
        INSERT5(t0, t1, t2, t3, t4, kb0 | s0.z);
        INSERT5(t0, t1, t2, t3, t4, kb0 | s0.w);
        INSERT5(t0, t1, t2, t3, t4, kb1 | s1.x);
        INSERT5(t0, t1, t2, t3, t4, kb1 | s1.y);
        INSERT5(t0, t1, t2, t3, t4, kb1 | s1.z);
        INSERT5(t0, t1, t2, t3, t4, kb1 | s1.w);

        // scanned-candidate count: scalar-pipe only, no shfl
        cum += __popcll(__ballot(s0.x != ~0u)) + __popcll(__ballot(s0.y != ~0u))
             + __popcll(__ballot(s0.z != ~0u)) + __popcll(__ballot(s0.w != ~0u))
             + __popcll(__ballot(s1.x != ~0u)) + __popcll(__ballot(s1.y != ~0u))
             + __popcll(__ballot(s1.z != ~0u)) + __popcll(__ballot(s1.w != ~0u));

        // cells with all 4 lo-slots valid may hold >4 points (rare)
        const uint32_t mx0 = umax_(umax_(s0.x, s0.y), umax_(s0.z, s0.w));
        const uint32_t mx1 = umax_(umax_(s1.x, s1.y), umax_(s1.z, s1.w));
        if (__any((mx0 != ~0u) | (mx1 != ~0u))) {
            if (mx0 != ~0u) {
                const uint32_t n = umin_(cnt[cell0], 8u);
                for (uint32_t m = 4; m < n; ++m)
                    INSERT5(t0, t1, t2, t3, t4,
                            kb0 | slotHi[(size_t)cell0 * 4 + (m - 4u)]);
            }
            if (mx1 != ~0u) {
                const uint32_t n = umin_(cnt[cell1], 8u);
                for (uint32_t m = 4; m < n; ++m)
                    INSERT5(t0, t1, t2, t3, t4,
                            kb1 | slotHi[(size_t)cell1 * 4 + (m - 4u)]);
            }
        }

        // shell-aligned boundary + >=5 scanned candidates => provably done
        if (cum >= 5 && ((kCanStop >> c) & 1ull)) break;
    }

    // ONE cross-lane merge per row
    waveMerge5_(t0, t1, t2, t3, t4);
    uint32_t g0 = t0, g1 = t1, g2 = t2, g3 = t3, g4 = t4;

    // ---- fold in overflow points (cells that spilled past 8 slots) ----
    const uint32_t ovf = ovfCnt[b];
    if (ovf > (uint32_t)kOvfCap) {
        // unreachable in practice; exact full rescan
        const int* cb = coords_b + (size_t)b * kNb * 3;
        uint32_t u0 = 0xFFFFFFFFu, u1 = u0, u2 = u0, u3 = u0, u4 = u0;
        for (int j = lane; j < kNb; j += 64) {
            const int dx = ax - cb[3 * j + 0];
            const int dy = ay - cb[3 * j + 1];
            const int dz = az - cb[3 * j + 2];
            const uint32_t d2 = (uint32_t)(dx * dx + dy * dy + dz * dz);
            INSERT5(u0, u1, u2, u3, u4, (d2 << 13) | (uint32_t)j);
        }
        waveMerge5_(u0, u1, u2, u3, u4);
        g0 = u0; g1 = u1; g2 = u2; g3 = u3; g4 = u4;
    } else {
        if (ovf > 0) {
            const int* cb = coords_b + (size_t)b * kNb * 3;
            uint32_t l0 = 0xFFFFFFFFu, l1 = l0, l2 = l0, l3 = l0, l4 = l0;
            for (uint32_t i = (uint32_t)lane; i < ovf; i += 64) {
                const uint32_t j = ovfIdx[b * kOvfCap + i];
                const int dx = ax - cb[3 * j + 0];
                const int dy = ay - cb[3 * j + 1];
                const int dz = az - cb[3 * j + 2];
                const uint32_t d2 = (uint32_t)(dx * dx + dy * dy + dz * dz);
                INSERT5(l0, l1, l2, l3, l4, (d2 << 13) | j);
            }
            waveMerge5_(l0, l1, l2, l3, l4);
            merge5_(g0, g1, g2, g3, g4, l0, l1, l2, l3, l4);
        }
        if ((g4 >> 13) > (uint32_t)kDMax) {
            // < 5 points within d<=8 of this row (prob ~0): exact rescan
            const int* cb = coords_b + (size_t)b * kNb * 3;
            uint32_t u0 = 0xFFFFFFFFu, u1 = u0, u2 = u0, u3 = u0, u4 = u0;
            for (int j = lane; j < kNb; j += 64) {
                const int dx = ax - cb[3 * j + 0];
                const int dy = ay - cb[3 * j + 1];
                const int dz = az - cb[3 * j + 2];
                const uint32_t d2 = (uint32_t)(dx * dx + dy * dy + dz * dz);
                INSERT5(u0, u1, u2, u3, u4, (d2 << 13) | (uint32_t)j);
            }
            waveMerge5_(u0, u1, u2, u3, u4);
            g0 = u0; g1 = u1; g2 = u2; g3 = u3; g4 = u4;
        }
    }

    // ---- weights + gather: lane == channel ----
    const float* fb = feat_b + (size_t)b * kNb * kC;
    const uint32_t keys[5] = {g0, g1, g2, g3, g4};
    float acc = 0.0f;
    #pragma unroll
    for (int t = 0; t < 5; ++t) {
        const uint32_t key = keys[t];
        const int j = (int)(key & 8191u);
        const float dist = sqrtf((float)(key >> 13)) * (1.0f / 32.0f);
        const float w = 0.5f - fminf(dist, 0.5f);
        acc += w * fb[(size_t)j * kC + lane];             // coalesced 256B/row
    }

    const size_t orow = ((size_t)b * kNa + row) * (2 * kC);
    out[orow + lane] = feat_a[((size_t)b * kNa + row) * kC + lane];
    out[orow + kC + lane] = acc;
}

// ---------------- brute kernel (fallback if ws too small) ----------------

__global__ __launch_bounds__(512, 8)
void dist_match_brute(const int* __restrict__ coords_a,
                      const int* __restrict__ coords_b,
                      const float* __restrict__ feat_a,
                      const float* __restrict__ feat_b,
                      float* __restrict__ out)
{
    __shared__ int spack[kNb];
    const int b = blockIdx.x >> 10;
    const int rowBase = (blockIdx.x & 1023) * 8;
    const int tid = threadIdx.x;
    const int lane = tid & 63;
    const int wave = tid >> 6;

    const int* cb = coords_b + (size_t)b * kNb * 3;
    for (int j = tid; j < kNb; j += 512) {
        spack[j] = cb[3 * j + 0] | (cb[3 * j + 1] << 8) | (cb[3 * j + 2] << 16);
    }
    __syncthreads();

    const int row = rowBase + wave;
    const int* ca = coords_a + ((size_t)b * kNa + row) * 3;
    const int ax = ca[0], ay = ca[1], az = ca[2];
    const int a2 = ax * ax + ay * ay + az * az;
    const int paneg2 = ((-2 * ax) & 255) | (((-2 * ay) & 255) << 8)
                     | (((-2 * az) & 255) << 16);

    uint32_t t0 = 0xFFFFFFFFu, t1 = t0, t2 = t0, t3 = t0, t4 = t0;
    for (int k = 0; k < kNb / 256; ++k) {
        const int baseI = k * 256 + lane * 4;
        const int4 p4 = *reinterpret_cast<const int4*>(spack + baseI);
        const int ps[4] = {p4.x, p4.y, p4.z, p4.w};
        #pragma unroll
        for (int u = 0; u < 4; ++u) {
            const int p = ps[u];
            const int dot1 = __builtin_amdgcn_sdot4(paneg2, p, a2, false);
            const int d2 = __builtin_amdgcn_sdot4(p, p, dot1, false);
            const uint32_t key = ((uint32_t)d2 << 13) | (uint32_t)(baseI + u);
            INSERT5(t0, t1, t2, t3, t4, key);
        }
    }
    waveMerge5_(t0, t1, t2, t3, t4);
    const float* fb = feat_b + (size_t)b * kNb * kC;
    const uint32_t keys[5] = {t0, t1, t2, t3, t4};
    float acc = 0.0f;
    #pragma unroll
    for (int t = 0; t < 5; ++t) {
        const uint32_t key = keys[t];
        const int j = (int)(key & 8191u);
        const float dist = sqrtf((float)(key >> 13)) * (1.0f / 32.0f);
        const float w = 0.5f - fminf(dist, 0.5f);
        acc += w * fb[(size_t)j * kC + lane];
    }
    const size_t orow = ((size_t)b * kNa + row) * (2 * kC);
    out[orow + lane] = feat_a[((size_t)b * kNa + row) * kC + lane];
    out[orow + kC + lane] = acc;
}

extern "C" void kernel_launch(void* const* d_in, const int* in_sizes, int n_in,
                              void* d_out, int out_size, void* d_ws, size_t ws_size,
                              hipStream_t stream) {
    const int* coords_a = (const int*)d_in[0];
    const int* coords_b = (const int*)d_in[1];
    const float* feat_a = (const float*)d_in[2];
    const float* feat_b = (const float*)d_in[3];
    float* out = (float*)d_out;

    if (ws_size < kWsBytes) {
        dist_match_brute<<<kB * 1024, 512, 0, stream>>>(coords_a, coords_b,
                                                        feat_a, feat_b, out);
        return;
    }

    uint32_t* ws32 = (uint32_t*)d_ws;
    uint32_t* cnt    = ws32 + kCntOff;
    uint32_t* ovfCnt = ws32 + kOvfCntOff;
    uint32_t* ovfIdx = ws32 + kOvfIdxOff;
    uint32_t* slotLo = ws32 + kSlotLoOff;
    uint32_t* slotHi = ws32 + kSlotHiOff;

    k_clear<<<kClrBlocks, 256, 0, stream>>>((uint4*)d_ws);
    k_scatter<<<kB * kNb / 256, 256, 0, stream>>>(coords_b, cnt, slotLo, slotHi,
                                                  ovfCnt, ovfIdx);
    dist_match_bucket<<<kB * 1024, 512, 0, stream>>>(coords_a, coords_b,
                                                     feat_a, feat_b,
                                                     cnt, slotLo, slotHi,
                                                     ovfCnt, ovfIdx, out);
}

// Round 10
// 30.877 us; speedup vs baseline: 1.2624x; 1.2624x over previous
//
#include <hip/hip_runtime.h>
#include <stdint.h>

// DistMatchLayer via spatial bucketing, round 10: 16-lane groups, 1 row/group.
//  - 4 rows per wave (8192 waves total; grid = 1024 x 512 = one full
//    occupancy round). Per-row fixed costs (prologue, merge, epilogue) /4.
//  - Chunk = 32 shell-aligned table entries (2/lane): chunk 0 = ball d2<=3
//    (27 cells, P(>=5 pts) ~ 0.8), chunk 1 reaches d2<=5 (P ~ 0.998).
//    ~39 cells scanned/row vs 128 in round 9.
//  - Group merge = 4-stage butterfly (16 lanes) instead of 6-stage (64).
//  - Early exit: per-lane candidate count (v_cmp adds), 4-stage group
//    shfl-add ONLY at canStop shell boundaries (~1.2 per row). Exact:
//    at a strict-d2-increase boundary with >=5 scanned candidates, the 5
//    best scanned keys beat every unscanned key; hi-slot/ovf candidates
//    uncounted (undercount only delays the stop - safe) but inserted.
//  - Epilogue: lane = 4 channels via float4 (16 lanes x 16B coalesced).
// Exact & stable: full keys (d2<<13)|j, order-independent top-5-of-union,
// ovf fold + per-group brute fallback close every corner case.

namespace {
constexpr int kB = 4;
constexpr int kNa = 8192;
constexpr int kNb = 8192;
constexpr int kC = 64;

constexpr int kRad = 8;                 // offsets |d| <= 8, d2 <= 64
constexpr int kDMax = 64;
constexpr int kGrid = 48;               // 32 + 2*8 padded grid
constexpr int kGrid2 = kGrid * kGrid;   // 2304
constexpr int kGrid3 = kGrid2 * kGrid;  // 110592
constexpr int kOff = kRad * kGrid2 + kRad * kGrid + kRad;  // 19208

constexpr int kChunkSz = 32;
constexpr int kMaxChunks = 128;
constexpr int kTabCap = kMaxChunks * kChunkSz;   // 4096

constexpr int kOvfCap = 256;

// ws layout (u32 words) -- same as rounds 8/9
constexpr size_t kCntOff    = 0;                                     // [442368]
constexpr size_t kOvfCntOff = 442368;                                // [4]
constexpr size_t kOvfIdxOff = 442372;                                // [1024]
constexpr size_t kSlotLoOff = 443396;                                // 16B-aligned
constexpr size_t kSlotHiOff = kSlotLoOff + (size_t)kB * kGrid3 * 4;
constexpr size_t kWsWords   = kSlotHiOff + (size_t)kB * kGrid3 * 4;
constexpr size_t kWsBytes   = kWsWords * 4ull;                       // ~15.9 MB

constexpr int kZeroVecEnd = (int)((kOvfCntOff + 4) / 4);
constexpr int kFFVecBeg   = (int)(kSlotLoOff / 4);
constexpr int kFFVecEnd   = (int)(kSlotHiOff / 4);
constexpr int kClrBlocks  = (kFFVecEnd + 255) / 256;

struct Tab {
    uint32_t e[kTabCap];
    unsigned long long canStop[2];
    int nChunks;
};
constexpr Tab buildTab() {
    Tab t{};
    for (int i = 0; i < kTabCap; ++i) t.e[i] = 0x7FFFFFFFu;  // sentinel
    t.canStop[0] = 0; t.canStop[1] = 0;
    int cnt[kDMax + 1] = {};
    for (int dx = -kRad; dx <= kRad; ++dx)
        for (int dy = -kRad; dy <= kRad; ++dy)
            for (int dz = -kRad; dz <= kRad; ++dz) {
                const int d2 = dx * dx + dy * dy + dz * dz;
                if (d2 <= kDMax) cnt[d2]++;
            }
    int pos[kDMax + 1] = {};
    int fill = 0;
    for (int d = 0; d <= kDMax; ++d) {
        if (cnt[d] == 0) { pos[d] = -1; continue; }
        const int room = kChunkSz - (fill % kChunkSz);
        if (room < cnt[d] && room != kChunkSz) fill += room;  // shell-align
        pos[d] = fill;
        fill += cnt[d];
    }
    t.nChunks = (fill + kChunkSz - 1) / kChunkSz;
    for (int dx = -kRad; dx <= kRad; ++dx)
        for (int dy = -kRad; dy <= kRad; ++dy)
            for (int dz = -kRad; dz <= kRad; ++dz) {
                const int d2 = dx * dx + dy * dy + dz * dz;
                if (d2 <= kDMax) {
                    const int sd = dx * kGrid2 + dy * kGrid + dz + kOff;
                    t.e[pos[d2]++] = ((uint32_t)d2 << 18) | (uint32_t)sd;
                }
            }
    // canStop[c]: min real d2 after chunk c STRICTLY > max real d2 up to c
    for (int c = 0; c < t.nChunks; ++c) {
        int lastReal = -1;
        for (int i = (c + 1) * kChunkSz - 1; i >= 0; --i) {
            const unsigned d = t.e[i] >> 18;
            if (d <= (unsigned)kDMax) { lastReal = (int)d; break; }
        }
        int nextReal = kDMax + 1;
        for (int i = (c + 1) * kChunkSz; i < kTabCap; ++i) {
            const unsigned d = t.e[i] >> 18;
            if (d <= (unsigned)kDMax) { nextReal = (int)d; break; }
        }
        if (nextReal > lastReal) t.canStop[c >> 6] |= (1ull << (c & 63));
    }
    return t;
}
__device__ constexpr Tab kTab = buildTab();          // ~16 KB .rodata
constexpr int kNChunks = buildTab().nChunks;
constexpr unsigned long long kCS0 = buildTab().canStop[0];
constexpr unsigned long long kCS1 = buildTab().canStop[1];
static_assert(buildTab().nChunks <= kMaxChunks, "table overflow");
}  // namespace

__device__ __forceinline__ uint32_t umin_(uint32_t a, uint32_t b) { return a < b ? a : b; }
__device__ __forceinline__ uint32_t umax_(uint32_t a, uint32_t b) { return a > b ? a : b; }

#define INSERT5(T0, T1, T2, T3, T4, KEY) do {                 \
    const uint32_t m0_ = umax_(T0, KEY); T0 = umin_(T0, KEY); \
    const uint32_t m1_ = umax_(T1, m0_); T1 = umin_(T1, m0_); \
    const uint32_t m2_ = umax_(T2, m1_); T2 = umin_(T2, m1_); \
    const uint32_t m3_ = umax_(T3, m2_); T3 = umin_(T3, m2_); \
    T4 = umin_(T4, m3_); } while (0)

__device__ __forceinline__ void merge5_(uint32_t& t0, uint32_t& t1, uint32_t& t2,
                                        uint32_t& t3, uint32_t& t4,
                                        uint32_t b0, uint32_t b1, uint32_t b2,
                                        uint32_t b3, uint32_t b4) {
    const uint32_t c0 = umin_(t0, b0);
    const uint32_t c1 = umin_(umin_(umax_(t0, b0), t1), b1);
    const uint32_t c2 = umin_(umin_(umax_(t0, b1), umax_(t1, b0)), umin_(t2, b2));
    const uint32_t c3 = umin_(umin_(umax_(t0, b2), umax_(t1, b1)),
                              umin_(umax_(t2, b0), umin_(t3, b3)));
    const uint32_t c4 = umin_(umin_(umax_(t0, b3), umax_(t1, b2)),
                              umin_(umin_(umax_(t2, b1), umax_(t3, b0)),
                                    umin_(t4, b4)));
    t0 = c0; t1 = c1; t2 = c2; t3 = c3; t4 = c4;
}

// 4-stage butterfly: all 16 lanes of a group end with the group's sorted top-5
__device__ __forceinline__ void groupMerge5_(uint32_t& t0, uint32_t& t1, uint32_t& t2,
                                             uint32_t& t3, uint32_t& t4) {
    #pragma unroll
    for (int s = 1; s < 16; s <<= 1) {
        const uint32_t b0 = (uint32_t)__shfl_xor((int)t0, s);
        const uint32_t b1 = (uint32_t)__shfl_xor((int)t1, s);
        const uint32_t b2 = (uint32_t)__shfl_xor((int)t2, s);
        const uint32_t b3 = (uint32_t)__shfl_xor((int)t3, s);
        const uint32_t b4 = (uint32_t)__shfl_xor((int)t4, s);
        merge5_(t0, t1, t2, t3, t4, b0, b1, b2, b3, b4);
    }
}

// 6-stage version for the brute kernel (wave per row)
__device__ __forceinline__ void waveMerge5_(uint32_t& t0, uint32_t& t1, uint32_t& t2,
                                            uint32_t& t3, uint32_t& t4) {
    #pragma unroll
    for (int s = 1; s < 64; s <<= 1) {
        const uint32_t b0 = (uint32_t)__shfl_xor((int)t0, s);
        const uint32_t b1 = (uint32_t)__shfl_xor((int)t1, s);
        const uint32_t b2 = (uint32_t)__shfl_xor((int)t2, s);
        const uint32_t b3 = (uint32_t)__shfl_xor((int)t3, s);
        const uint32_t b4 = (uint32_t)__shfl_xor((int)t4, s);
        merge5_(t0, t1, t2, t3, t4, b0, b1, b2, b3, b4);
    }
}

// ---------------- clear + scatter ----------------

__global__ __launch_bounds__(256)
void k_clear(uint4* __restrict__ ws) {
    const int i = blockIdx.x * 256 + threadIdx.x;
    if (i < kZeroVecEnd) ws[i] = uint4{0u, 0u, 0u, 0u};
    else if (i >= kFFVecBeg && i < kFFVecEnd) ws[i] = uint4{~0u, ~0u, ~0u, ~0u};
}

__global__ void k_scatter(const int* __restrict__ coords_b,
                          uint32_t* __restrict__ cnt,
                          uint32_t* __restrict__ slotLo,
                          uint32_t* __restrict__ slotHi,
                          uint32_t* __restrict__ ovfCnt,
                          uint32_t* __restrict__ ovfIdx) {
    const int i = blockIdx.x * blockDim.x + threadIdx.x;
    if (i >= kB * kNb) return;
    const int b = i >> 13;
    const int j = i & (kNb - 1);
    const int* p = coords_b + (size_t)i * 3;
    const int cell = b * kGrid3
                   + (p[0] + kRad) * kGrid2 + (p[1] + kRad) * kGrid + (p[2] + kRad);
    const uint32_t pos = atomicAdd(&cnt[cell], 1u);
    if (pos < 4u) {
        slotLo[(size_t)cell * 4 + pos] = (uint32_t)j;
    } else if (pos < 8u) {
        slotHi[(size_t)cell * 4 + (pos - 4u)] = (uint32_t)j;
    } else {
        const uint32_t op = atomicAdd(&ovfCnt[b], 1u);
        if (op < (uint32_t)kOvfCap) ovfIdx[b * kOvfCap + op] = (uint32_t)j;
    }
}

// ---------------- main kernel: 16-lane group per row ----------------

__global__ __launch_bounds__(512, 8)
void dist_match_bucket(const int* __restrict__ coords_a,
                       const int* __restrict__ coords_b,
                       const float* __restrict__ feat_a,
                       const float* __restrict__ feat_b,
                       const uint32_t* __restrict__ cnt,
                       const uint32_t* __restrict__ slotLo,
                       const uint32_t* __restrict__ slotHi,
                       const uint32_t* __restrict__ ovfCnt,
                       const uint32_t* __restrict__ ovfIdx,
                       float* __restrict__ out)
{
    const int b = blockIdx.x >> 8;                 // 256 blocks/batch
    const int rowBase = (blockIdx.x & 255) * 32;   // 32 rows/block
    const int lane = threadIdx.x & 63;
    const int wave = threadIdx.x >> 6;
    const int sub = lane & 15;                     // lane within group
    const int grp = lane >> 4;                     // 0..3
    const int row = rowBase + wave * 4 + grp;

    const int* ca = coords_a + ((size_t)b * kNa + row) * 3;
    const int ax = ca[0], ay = ca[1], az = ca[2];
    const int aCell = (ax + kRad) * kGrid2 + (ay + kRad) * kGrid + (az + kRad);
    const int base = b * kGrid3 + aCell - kOff;

    uint32_t t0 = 0xFFFFFFFFu, t1 = t0, t2 = t0, t3 = t0, t4 = t0;
    int myCnt = 0;
    bool done = false;

    for (int c = 0; c < kNChunks; ++c) {
        if (__all(done)) break;
        if (!done) {
            const uint2 ee = *reinterpret_cast<const uint2*>(
                                 kTab.e + c * kChunkSz + sub * 2);
            const uint32_t d20 = ee.x >> 18, d21 = ee.y >> 18;
            const int cell0 = base + (int)(ee.x & 0x3FFFFu);
            const int cell1 = base + (int)(ee.y & 0x3FFFFu);
            uint4 s0 = uint4{~0u, ~0u, ~0u, ~0u};
            uint4 s1 = uint4{~0u, ~0u, ~0u, ~0u};
            if (d20 <= (uint32_t)kDMax)
                s0 = *reinterpret_cast<const uint4*>(slotLo + (size_t)cell0 * 4);
            if (d21 <= (uint32_t)kDMax)
                s1 = *reinterpret_cast<const uint4*>(slotLo + (size_t)cell1 * 4);

            const uint32_t kb0 = d20 << 13, kb1 = d21 << 13;
            INSERT5(t0, t1, t2, t3, t4, kb0 | s0.x);
            INSERT5(t0, t1, t2, t3, t4, kb0 | s0.y);
            INSERT5(t0, t1, t2, t3, t4, kb0 | s0.z);
            INSERT5(t0, t1, t2, t3, t4, kb0 | s0.w);
            INSERT5(t0, t1, t2, t3, t4, kb1 | s1.x);
            INSERT5(t0, t1, t2, t3, t4, kb1 | s1.y);
            INSERT5(t0, t1, t2, t3, t4, kb1 | s1.z);
            INSERT5(t0, t1, t2, t3, t4, kb1 | s1.w);

            myCnt += (s0.x != ~0u) + (s0.y != ~0u) + (s0.z != ~0u) + (s0.w != ~0u)
                   + (s1.x != ~0u) + (s1.y != ~0u) + (s1.z != ~0u) + (s1.w != ~0u);

            // cells with all 4 lo-slots valid may hold >4 points (rare)
            const uint32_t mx0 = umax_(umax_(s0.x, s0.y), umax_(s0.z, s0.w));
            const uint32_t mx1 = umax_(umax_(s1.x, s1.y), umax_(s1.z, s1.w));
            if (__any((mx0 != ~0u) | (mx1 != ~0u))) {
                if (mx0 != ~0u) {
                    const uint32_t n = umin_(cnt[cell0], 8u);
                    for (uint32_t m = 4; m < n; ++m)
                        INSERT5(t0, t1, t2, t3, t4,
                                kb0 | slotHi[(size_t)cell0 * 4 + (m - 4u)]);
                }
                if (mx1 != ~0u) {
                    const uint32_t n = umin_(cnt[cell1], 8u);
                    for (uint32_t m = 4; m < n; ++m)
                        INSERT5(t0, t1, t2, t3, t4,
                                kb1 | slotHi[(size_t)cell1 * 4 + (m - 4u)]);
                }
            }

            const bool canStop = (c < 64) ? (((kCS0 >> c) & 1ull) != 0)
                                          : (((kCS1 >> (c - 64)) & 1ull) != 0);
            if (canStop) {
                int gs = myCnt;                     // group sum (16 lanes)
                gs += __shfl_xor(gs, 1);
                gs += __shfl_xor(gs, 2);
                gs += __shfl_xor(gs, 4);
                gs += __shfl_xor(gs, 8);
                if (gs >= 5) done = true;
            }
        }
    }

    // ONE group merge per row
    groupMerge5_(t0, t1, t2, t3, t4);
    uint32_t g0 = t0, g1 = t1, g2 = t2, g3 = t3, g4 = t4;

    // ---- overflow fold + fallback (all rare/cold) ----
    const uint32_t ovf = ovfCnt[b];
    bool needFull = (ovf > (uint32_t)kOvfCap);
    if (!needFull && ovf > 0) {
        const int* cb = coords_b + (size_t)b * kNb * 3;
        uint32_t l0 = 0xFFFFFFFFu, l1 = l0, l2 = l0, l3 = l0, l4 = l0;
        for (uint32_t i = (uint32_t)sub; i < ovf; i += 16) {
            const uint32_t j = ovfIdx[b * kOvfCap + i];
            const int dx = ax - cb[3 * j + 0];
            const int dy = ay - cb[3 * j + 1];
            const int dz = az - cb[3 * j + 2];
            const uint32_t d2 = (uint32_t)(dx * dx + dy * dy + dz * dz);
            INSERT5(l0, l1, l2, l3, l4, (d2 << 13) | j);
        }
        groupMerge5_(l0, l1, l2, l3, l4);
        merge5_(g0, g1, g2, g3, g4, l0, l1, l2, l3, l4);
    }
    if (!needFull && (g4 >> 13) > (uint32_t)kDMax) needFull = true;
    if (__any(needFull)) {
        if (needFull) {                            // group-uniform predicate
            const int* cb = coords_b + (size_t)b * kNb * 3;
            uint32_t u0 = 0xFFFFFFFFu, u1 = u0, u2 = u0, u3 = u0, u4 = u0;
            for (int j = sub; j < kNb; j += 16) {
                const int dx = ax - cb[3 * j + 0];
                const int dy = ay - cb[3 * j + 1];
                const int dz = az - cb[3 * j + 2];
                const uint32_t d2 = (uint32_t)(dx * dx + dy * dy + dz * dz);
                INSERT5(u0, u1, u2, u3, u4, (d2 << 13) | (uint32_t)j);
            }
            groupMerge5_(u0, u1, u2, u3, u4);
            g0 = u0; g1 = u1; g2 = u2; g3 = u3; g4 = u4;
        }
    }

    // ---- weights + gather: lane = 4 channels (float4) ----
    const float* fb = feat_b + (size_t)b * kNb * kC;
    const uint32_t keys[5] = {g0, g1, g2, g3, g4};
    float4 acc = float4{0.f, 0.f, 0.f, 0.f};
    #pragma unroll
    for (int t = 0; t < 5; ++t) {
        const uint32_t key = keys[t];
        const int j = (int)(key & 8191u);
        const float dist = sqrtf((float)(key >> 13)) * (1.0f / 32.0f);
        const float w = 0.5f - fminf(dist, 0.5f);
        const float4 v = *reinterpret_cast<const float4*>(
                             fb + (size_t)j * kC + sub * 4);
        acc.x += w * v.x; acc.y += w * v.y; acc.z += w * v.z; acc.w += w * v.w;
    }

    const size_t arow = ((size_t)b * kNa + row) * kC;
    const float4 fa = *reinterpret_cast<const float4*>(feat_a + arow + sub * 4);
    const size_t orow = ((size_t)b * kNa + row) * (2 * kC);
    *reinterpret_cast<float4*>(out + orow + sub * 4) = fa;
    *reinterpret_cast<float4*>(out + orow + kC + sub * 4) = acc;
}

// ---------------- brute kernel (fallback if ws too small) ----------------

__global__ __launch_bounds__(512, 8)
void dist_match_brute(const int* __restrict__ coords_a,
                      const int* __restrict__ coords_b,
                      const float* __restrict__ feat_a,
                      const float* __restrict__ feat_b,
                      float* __restrict__ out)
{
    __shared__ int spack[kNb];
    const int b = blockIdx.x >> 10;
    const int rowBase = (blockIdx.x & 1023) * 8;
    const int tid = threadIdx.x;
    const int lane = tid & 63;
    const int wave = tid >> 6;

    const int* cb = coords_b + (size_t)b * kNb * 3;
    for (int j = tid; j < kNb; j += 512) {
        spack[j] = cb[3 * j + 0] | (cb[3 * j + 1] << 8) | (cb[3 * j + 2] << 16);
    }
    __syncthreads();

    const int row = rowBase + wave;
    const int* ca = coords_a + ((size_t)b * kNa + row) * 3;
    const int ax = ca[0], ay = ca[1], az = ca[2];
    const int a2 = ax * ax + ay * ay + az * az;
    const int paneg2 = ((-2 * ax) & 255) | (((-2 * ay) & 255) << 8)
                     | (((-2 * az) & 255) << 16);

    uint32_t t0 = 0xFFFFFFFFu, t1 = t0, t2 = t0, t3 = t0, t4 = t0;
    for (int k = 0; k < kNb / 256; ++k) {
        const int baseI = k * 256 + lane * 4;
        const int4 p4 = *reinterpret_cast<const int4*>(spack + baseI);
        const int ps[4] = {p4.x, p4.y, p4.z, p4.w};
        #pragma unroll
        for (int u = 0; u < 4; ++u) {
            const int p = ps[u];
            const int dot1 = __builtin_amdgcn_sdot4(paneg2, p, a2, false);
            const int d2 = __builtin_amdgcn_sdot4(p, p, dot1, false);
            const uint32_t key = ((uint32_t)d2 << 13) | (uint32_t)(baseI + u);
            INSERT5(t0, t1, t2, t3, t4, key);
        }
    }
    waveMerge5_(t0, t1, t2, t3, t4);
    const float* fb = feat_b + (size_t)b * kNb * kC;
    const uint32_t keys[5] = {t0, t1, t2, t3, t4};
    float acc = 0.0f;
    #pragma unroll
    for (int t = 0; t < 5; ++t) {
        const uint32_t key = keys[t];
        const int j = (int)(key & 8191u);
        const float dist = sqrtf((float)(key >> 13)) * (1.0f / 32.0f);
        const float w = 0.5f - fminf(dist, 0.5f);
        acc += w * fb[(size_t)j * kC + lane];
    }
    const size_t orow = ((size_t)b * kNa + row) * (2 * kC);
    out[orow + lane] = feat_a[((size_t)b * kNa + row) * kC + lane];
    out[orow + kC + lane] = acc;
}

extern "C" void kernel_launch(void* const* d_in, const int* in_sizes, int n_in,
                              void* d_out, int out_size, void* d_ws, size_t ws_size,
                              hipStream_t stream) {
    const int* coords_a = (const int*)d_in[0];
    const int* coords_b = (const int*)d_in[1];
    const float* feat_a = (const float*)d_in[2];
    const float* feat_b = (const float*)d_in[3];
    float* out = (float*)d_out;

    if (ws_size < kWsBytes) {
        dist_match_brute<<<kB * 1024, 512, 0, stream>>>(coords_a, coords_b,
                                                        feat_a, feat_b, out);
        return;
    }

    uint32_t* ws32 = (uint32_t*)d_ws;
    uint32_t* cnt    = ws32 + kCntOff;
    uint32_t* ovfCnt = ws32 + kOvfCntOff;
    uint32_t* ovfIdx = ws32 + kOvfIdxOff;
    uint32_t* slotLo = ws32 + kSlotLoOff;
    uint32_t* slotHi = ws32 + kSlotHiOff;

    k_clear<<<kClrBlocks, 256, 0, stream>>>((uint4*)d_ws);
    k_scatter<<<kB * kNb / 256, 256, 0, stream>>>(coords_b, cnt, slotLo, slotHi,
                                                  ovfCnt, ovfIdx);
    dist_match_bucket<<<kB * 256, 512, 0, stream>>>(coords_a, coords_b,
                                                    feat_a, feat_b,
                                                    cnt, slotLo, slotHi,
                                                    ovfCnt, ovfIdx, out);
}

// Round 11
// 30.525 us; speedup vs baseline: 1.2770x; 1.0115x over previous
//
#include <hip/hip_runtime.h>
#include <stdint.h>

// DistMatchLayer via spatial bucketing, round 11.
// Changes vs round 10:
//  - u16 packed slots: 4 slots x 2B = 8B/cell (slot table 7.0 -> 3.5 MB,
//    mostly L2-resident; clear 8.85 -> 5.3 MB). Sentinel 0xFFFF sign-extends
//    to 0xFFFFFFFF so key = kb | sext16(w) preserves the sentinel-absorbing
//    branchless insert. "Cell full" = slot3 valid (slots fill in order).
//  - Fused chunk0+chunk1 fast path: all 4 slot gathers issued before any
//    insert (one L2 round trip in flight); insert chunk0, group-count, and
//    only if cum<5 insert the already-fetched chunk1. 99.4% of rows finish
//    here; the rest continue the sequential shell loop from c=2.
//  - ovfCnt / feat_a loads hoisted to kernel start (overlap search latency).
// Exact & stable (unchanged machinery): full keys (d2<<13)|j, shell-aligned
// count-based stop (undercount-safe), hi-slots via cnt guard, ovf fold,
// per-group brute fallback.

namespace {
constexpr int kB = 4;
constexpr int kNa = 8192;
constexpr int kNb = 8192;
constexpr int kC = 64;

constexpr int kRad = 8;                 // offsets |d| <= 8, d2 <= 64
constexpr int kDMax = 64;
constexpr int kGrid = 48;               // 32 + 2*8 padded grid
constexpr int kGrid2 = kGrid * kGrid;   // 2304
constexpr int kGrid3 = kGrid2 * kGrid;  // 110592
constexpr int kOff = kRad * kGrid2 + kRad * kGrid + kRad;  // 19208

constexpr int kChunkSz = 32;
constexpr int kMaxChunks = 128;
constexpr int kTabCap = kMaxChunks * kChunkSz;   // 4096

constexpr int kOvfCap = 256;

// ws layout (u32 words)
constexpr size_t kCntOff    = 0;                                     // [442368]
constexpr size_t kOvfCntOff = 442368;                                // [4]
constexpr size_t kOvfIdxOff = 442372;                                // [1024]
constexpr size_t kSlot16Off = 443396;          // u16 slots, 2 words/cell; 16B-aligned
constexpr size_t kSlotHiOff = kSlot16Off + (size_t)kB * kGrid3 * 2;  // 1,328,132
constexpr size_t kWsWords   = kSlotHiOff + (size_t)kB * kGrid3 * 4;  // 3,097,604
constexpr size_t kWsBytes   = kWsWords * 4ull;                       // ~12.4 MB

constexpr int kZeroVecEnd = (int)((kOvfCntOff + 4) / 4);   // 110593
constexpr int kFFVecBeg   = (int)(kSlot16Off / 4);         // 110849
constexpr int kFFVecEnd   = (int)(kSlotHiOff / 4);         // 332033
constexpr int kClrBlocks  = (kFFVecEnd + 255) / 256;       // 1297

struct Tab {
    uint32_t e[kTabCap];
    unsigned long long canStop[2];
    int nChunks;
};
constexpr Tab buildTab() {
    Tab t{};
    for (int i = 0; i < kTabCap; ++i) t.e[i] = 0x7FFFFFFFu;  // sentinel
    t.canStop[0] = 0; t.canStop[1] = 0;
    int cnt[kDMax + 1] = {};
    for (int dx = -kRad; dx <= kRad; ++dx)
        for (int dy = -kRad; dy <= kRad; ++dy)
            for (int dz = -kRad; dz <= kRad; ++dz) {
                const int d2 = dx * dx + dy * dy + dz * dz;
                if (d2 <= kDMax) cnt[d2]++;
            }
    int pos[kDMax + 1] = {};
    int fill = 0;
    for (int d = 0; d <= kDMax; ++d) {
        if (cnt[d] == 0) { pos[d] = -1; continue; }
        const int room = kChunkSz - (fill % kChunkSz);
        if (room < cnt[d] && room != kChunkSz) fill += room;  // shell-align
        pos[d] = fill;
        fill += cnt[d];
    }
    t.nChunks = (fill + kChunkSz - 1) / kChunkSz;
    for (int dx = -kRad; dx <= kRad; ++dx)
        for (int dy = -kRad; dy <= kRad; ++dy)
            for (int dz = -kRad; dz <= kRad; ++dz) {
                const int d2 = dx * dx + dy * dy + dz * dz;
                if (d2 <= kDMax) {
                    const int sd = dx * kGrid2 + dy * kGrid + dz + kOff;
                    t.e[pos[d2]++] = ((uint32_t)d2 << 18) | (uint32_t)sd;
                }
            }
    for (int c = 0; c < t.nChunks; ++c) {
        int lastReal = -1;
        for (int i = (c + 1) * kChunkSz - 1; i >= 0; --i) {
            const unsigned d = t.e[i] >> 18;
            if (d <= (unsigned)kDMax) { lastReal = (int)d; break; }
        }
        int nextReal = kDMax + 1;
        for (int i = (c + 1) * kChunkSz; i < kTabCap; ++i) {
            const unsigned d = t.e[i] >> 18;
            if (d <= (unsigned)kDMax) { nextReal = (int)d; break; }
        }
        if (nextReal > lastReal) t.canStop[c >> 6] |= (1ull << (c & 63));
    }
    return t;
}
__device__ constexpr Tab kTab = buildTab();          // ~16 KB .rodata
constexpr int kNChunks = buildTab().nChunks;
constexpr unsigned long long kCS0 = buildTab().canStop[0];
constexpr unsigned long long kCS1 = buildTab().canStop[1];
static_assert(buildTab().nChunks <= kMaxChunks, "table overflow");
}  // namespace

__device__ __forceinline__ uint32_t umin_(uint32_t a, uint32_t b) { return a < b ? a : b; }
__device__ __forceinline__ uint32_t umax_(uint32_t a, uint32_t b) { return a > b ? a : b; }

#define INSERT5(T0, T1, T2, T3, T4, KEY) do {                 \
    const uint32_t m0_ = umax_(T0, KEY); T0 = umin_(T0, KEY); \
    const uint32_t m1_ = umax_(T1, m0_); T1 = umin_(T1, m0_); \
    const uint32_t m2_ = umax_(T2, m1_); T2 = umin_(T2, m1_); \
    const uint32_t m3_ = umax_(T3, m2_); T3 = umin_(T3, m2_); \
    T4 = umin_(T4, m3_); } while (0)

// unpack one u32 (2 u16 slots) and insert; sentinel 0xFFFF -> key 0xFFFFFFFF
#define UNPACK2_INS(W, KB, CNT) do {                                  \
    const uint32_t v0_ = (uint32_t)(int32_t)(int16_t)((W) & 0xFFFFu); \
    const uint32_t v1_ = (uint32_t)(int32_t)(int16_t)((W) >> 16);     \
    INSERT5(t0, t1, t2, t3, t4, (KB) | v0_);                          \
    INSERT5(t0, t1, t2, t3, t4, (KB) | v1_);                          \
    CNT += (v0_ != ~0u) + (v1_ != ~0u); } while (0)

__device__ __forceinline__ void merge5_(uint32_t& t0, uint32_t& t1, uint32_t& t2,
                                        uint32_t& t3, uint32_t& t4,
                                        uint32_t b0, uint32_t b1, uint32_t b2,
                                        uint32_t b3, uint32_t b4) {
    const uint32_t c0 = umin_(t0, b0);
    const uint32_t c1 = umin_(umin_(umax_(t0, b0), t1), b1);
    const uint32_t c2 = umin_(umin_(umax_(t0, b1), umax_(t1, b0)), umin_(t2, b2));
    const uint32_t c3 = umin_(umin_(umax_(t0, b2), umax_(t1, b1)),
                              umin_(umax_(t2, b0), umin_(t3, b3)));
    const uint32_t c4 = umin_(umin_(umax_(t0, b3), umax_(t1, b2)),
                              umin_(umin_(umax_(t2, b1), umax_(t3, b0)),
                                    umin_(t4, b4)));
    t0 = c0; t1 = c1; t2 = c2; t3 = c3; t4 = c4;
}

__device__ __forceinline__ void groupMerge5_(uint32_t& t0, uint32_t& t1, uint32_t& t2,
                                             uint32_t& t3, uint32_t& t4) {
    #pragma unroll
    for (int s = 1; s < 16; s <<= 1) {
        const uint32_t b0 = (uint32_t)__shfl_xor((int)t0, s);
        const uint32_t b1 = (uint32_t)__shfl_xor((int)t1, s);
        const uint32_t b2 = (uint32_t)__shfl_xor((int)t2, s);
        const uint32_t b3 = (uint32_t)__shfl_xor((int)t3, s);
        const uint32_t b4 = (uint32_t)__shfl_xor((int)t4, s);
        merge5_(t0, t1, t2, t3, t4, b0, b1, b2, b3, b4);
    }
}

__device__ __forceinline__ void waveMerge5_(uint32_t& t0, uint32_t& t1, uint32_t& t2,
                                            uint32_t& t3, uint32_t& t4) {
    #pragma unroll
    for (int s = 1; s < 64; s <<= 1) {
        const uint32_t b0 = (uint32_t)__shfl_xor((int)t0, s);
        const uint32_t b1 = (uint32_t)__shfl_xor((int)t1, s);
        const uint32_t b2 = (uint32_t)__shfl_xor((int)t2, s);
        const uint32_t b3 = (uint32_t)__shfl_xor((int)t3, s);
        const uint32_t b4 = (uint32_t)__shfl_xor((int)t4, s);
        merge5_(t0, t1, t2, t3, t4, b0, b1, b2, b3, b4);
    }
}

__device__ __forceinline__ int groupSum16_(int v) {
    v += __shfl_xor(v, 1);
    v += __shfl_xor(v, 2);
    v += __shfl_xor(v, 4);
    v += __shfl_xor(v, 8);
    return v;
}

// ---------------- clear + scatter ----------------

__global__ __launch_bounds__(256)
void k_clear(uint4* __restrict__ ws) {
    const int i = blockIdx.x * 256 + threadIdx.x;
    if (i < kZeroVecEnd) ws[i] = uint4{0u, 0u, 0u, 0u};
    else if (i >= kFFVecBeg && i < kFFVecEnd) ws[i] = uint4{~0u, ~0u, ~0u, ~0u};
}

__global__ void k_scatter(const int* __restrict__ coords_b,
                          uint32_t* __restrict__ cnt,
                          uint16_t* __restrict__ slot16,
                          uint32_t* __restrict__ slotHi,
                          uint32_t* __restrict__ ovfCnt,
                          uint32_t* __restrict__ ovfIdx) {
    const int i = blockIdx.x * blockDim.x + threadIdx.x;
    if (i >= kB * kNb) return;
    const int b = i >> 13;
    const int j = i & (kNb - 1);
    const int* p = coords_b + (size_t)i * 3;
    const int cell = b * kGrid3
                   + (p[0] + kRad) * kGrid2 + (p[1] + kRad) * kGrid + (p[2] + kRad);
    const uint32_t pos = atomicAdd(&cnt[cell], 1u);
    if (pos < 4u) {
        slot16[(size_t)cell * 4 + pos] = (uint16_t)j;   // byte-enable store, race-free
    } else if (pos < 8u) {
        slotHi[(size_t)cell * 4 + (pos - 4u)] = (uint32_t)j;
    } else {
        const uint32_t op = atomicAdd(&ovfCnt[b], 1u);
        if (op < (uint32_t)kOvfCap) ovfIdx[b * kOvfCap + op] = (uint32_t)j;
    }
}

// ---------------- main kernel: 16-lane group per row ----------------

__global__ __launch_bounds__(512, 8)
void dist_match_bucket(const int* __restrict__ coords_a,
                       const int* __restrict__ coords_b,
                       const float* __restrict__ feat_a,
                       const float* __restrict__ feat_b,
                       const uint32_t* __restrict__ cnt,
                       const uint16_t* __restrict__ slot16,
                       const uint32_t* __restrict__ slotHi,
                       const uint32_t* __restrict__ ovfCnt,
                       const uint32_t* __restrict__ ovfIdx,
                       float* __restrict__ out)
{
    const int b = blockIdx.x >> 8;                 // 256 blocks/batch
    const int rowBase = (blockIdx.x & 255) * 32;   // 32 rows/block
    const int lane = threadIdx.x & 63;
    const int wave = threadIdx.x >> 6;
    const int sub = lane & 15;
    const int grp = lane >> 4;
    const int row = rowBase + wave * 4 + grp;

    // early independent loads (overlap the search)
    const uint32_t ovf = ovfCnt[b];
    const size_t arow = ((size_t)b * kNa + row) * kC;
    const float4 fa = *reinterpret_cast<const float4*>(feat_a + arow + sub * 4);

    const int* ca = coords_a + ((size_t)b * kNa + row) * 3;
    const int ax = ca[0], ay = ca[1], az = ca[2];
    const int aCell = (ax + kRad) * kGrid2 + (ay + kRad) * kGrid + (az + kRad);
    const int base = b * kGrid3 + aCell - kOff;

    uint32_t t0 = 0xFFFFFFFFu, t1 = t0, t2 = t0, t3 = t0, t4 = t0;
    int myCnt = 0;

    // ---- fused chunks 0 + 1: all 4 slot gathers in flight before inserts ----
    const uint2 eA = *reinterpret_cast<const uint2*>(kTab.e + sub * 2);
    const uint2 eB = *reinterpret_cast<const uint2*>(kTab.e + kChunkSz + sub * 2);
    const uint32_t dA0 = eA.x >> 18, dA1 = eA.y >> 18;
    const uint32_t dB0 = eB.x >> 18, dB1 = eB.y >> 18;
    const int cA0 = base + (int)(eA.x & 0x3FFFFu);
    const int cA1 = base + (int)(eA.y & 0x3FFFFu);
    const int cB0 = base + (int)(eB.x & 0x3FFFFu);
    const int cB1 = base + (int)(eB.y & 0x3FFFFu);
    uint2 sA0 = uint2{~0u, ~0u}, sA1 = sA0, sB0 = sA0, sB1 = sA0;
    if (dA0 <= (uint32_t)kDMax)
        sA0 = *reinterpret_cast<const uint2*>(slot16 + (size_t)cA0 * 4);
    if (dA1 <= (uint32_t)kDMax)
        sA1 = *reinterpret_cast<const uint2*>(slot16 + (size_t)cA1 * 4);
    if (dB0 <= (uint32_t)kDMax)
        sB0 = *reinterpret_cast<const uint2*>(slot16 + (size_t)cB0 * 4);
    if (dB1 <= (uint32_t)kDMax)
        sB1 = *reinterpret_cast<const uint2*>(slot16 + (size_t)cB1 * 4);

    const uint32_t kbA0 = dA0 << 13, kbA1 = dA1 << 13;
    const uint32_t kbB0 = dB0 << 13, kbB1 = dB1 << 13;

    // chunk 0 inserts
    UNPACK2_INS(sA0.x, kbA0, myCnt); UNPACK2_INS(sA0.y, kbA0, myCnt);
    UNPACK2_INS(sA1.x, kbA1, myCnt); UNPACK2_INS(sA1.y, kbA1, myCnt);
    const bool fullA0 = (sA0.y >> 16) != 0xFFFFu;   // slot3 valid => maybe >4 pts
    const bool fullA1 = (sA1.y >> 16) != 0xFFFFu;
    if (__any(fullA0 | fullA1)) {
        if (fullA0) {
            const uint32_t n = umin_(cnt[cA0], 8u);
            for (uint32_t m = 4; m < n; ++m)
                INSERT5(t0, t1, t2, t3, t4, kbA0 | slotHi[(size_t)cA0 * 4 + (m - 4u)]);
        }
        if (fullA1) {
            const uint32_t n = umin_(cnt[cA1], 8u);
            for (uint32_t m = 4; m < n; ++m)
                INSERT5(t0, t1, t2, t3, t4, kbA1 | slotHi[(size_t)cA1 * 4 + (m - 4u)]);
        }
    }

    int gs = groupSum16_(myCnt);
    bool doneG = (gs >= 5);                          // chunk0 boundary is canStop

    // chunk 1 inserts (data already fetched; skip if group satisfied)
    if (__any(!doneG)) {
        if (!doneG) {
            UNPACK2_INS(sB0.x, kbB0, myCnt); UNPACK2_INS(sB0.y, kbB0, myCnt);
            UNPACK2_INS(sB1.x, kbB1, myCnt); UNPACK2_INS(sB1.y, kbB1, myCnt);
            const bool fullB0 = (sB0.y >> 16) != 0xFFFFu;
            const bool fullB1 = (sB1.y >> 16) != 0xFFFFu;
            if (__any(fullB0 | fullB1)) {
                if (fullB0) {
                    const uint32_t n = umin_(cnt[cB0], 8u);
                    for (uint32_t m = 4; m < n; ++m)
                        INSERT5(t0, t1, t2, t3, t4, kbB0 | slotHi[(size_t)cB0 * 4 + (m - 4u)]);
                }
                if (fullB1) {
                    const uint32_t n = umin_(cnt[cB1], 8u);
                    for (uint32_t m = 4; m < n; ++m)
                        INSERT5(t0, t1, t2, t3, t4, kbB1 | slotHi[(size_t)cB1 * 4 + (m - 4u)]);
                }
            }
            gs = groupSum16_(myCnt);
            doneG = (gs >= 5);                       // chunk1 boundary is canStop
        } else {
            doneG = true;
        }
    }

    // ---- rare continuation: sequential shell loop from c = 2 ----
    if (__any(!doneG)) {
        bool done = doneG;
        for (int c = 2; c < kNChunks; ++c) {
            if (__all(done)) break;
            if (!done) {
                const uint2 ee = *reinterpret_cast<const uint2*>(
                                     kTab.e + c * kChunkSz + sub * 2);
                const uint32_t d20 = ee.x >> 18, d21 = ee.y >> 18;
                const int cell0 = base + (int)(ee.x & 0x3FFFFu);
                const int cell1 = base + (int)(ee.y & 0x3FFFFu);
                uint2 s0 = uint2{~0u, ~0u}, s1 = s0;
                if (d20 <= (uint32_t)kDMax)
                    s0 = *reinterpret_cast<const uint2*>(slot16 + (size_t)cell0 * 4);
                if (d21 <= (uint32_t)kDMax)
                    s1 = *reinterpret_cast<const uint2*>(slot16 + (size_t)cell1 * 4);
                const uint32_t kb0 = d20 << 13, kb1 = d21 << 13;
                UNPACK2_INS(s0.x, kb0, myCnt); UNPACK2_INS(s0.y, kb0, myCnt);
                UNPACK2_INS(s1.x, kb1, myCnt); UNPACK2_INS(s1.y, kb1, myCnt);
                const bool full0 = (s0.y >> 16) != 0xFFFFu;
                const bool full1 = (s1.y >> 16) != 0xFFFFu;
                if (__any(full0 | full1)) {
                    if (full0) {
                        const uint32_t n = umin_(cnt[cell0], 8u);
                        for (uint32_t m = 4; m < n; ++m)
                            INSERT5(t0, t1, t2, t3, t4,
                                    kb0 | slotHi[(size_t)cell0 * 4 + (m - 4u)]);
                    }
                    if (full1) {
                        const uint32_t n = umin_(cnt[cell1], 8u);
                        for (uint32_t m = 4; m < n; ++m)
                            INSERT5(t0, t1, t2, t3, t4,
                                    kb1 | slotHi[(size_t)cell1 * 4 + (m - 4u)]);
                    }
                }
                const bool canStop = (c < 64) ? (((kCS0 >> c) & 1ull) != 0)
                                              : (((kCS1 >> (c - 64)) & 1ull) != 0);
                if (canStop) {
                    if (groupSum16_(myCnt) >= 5) done = true;
                }
            }
        }
    }

    // ONE group merge per row
    groupMerge5_(t0, t1, t2, t3, t4);
    uint32_t g0 = t0, g1 = t1, g2 = t2, g3 = t3, g4 = t4;

    // ---- overflow fold + fallback (rare/cold) ----
    bool needFull = (ovf > (uint32_t)kOvfCap);
    if (!needFull && ovf > 0) {
        const int* cb = coords_b + (size_t)b * kNb * 3;
        uint32_t l0 = 0xFFFFFFFFu, l1 = l0, l2 = l0, l3 = l0, l4 = l0;
        for (uint32_t i = (uint32_t)sub; i < ovf; i += 16) {
            const uint32_t j = ovfIdx[b * kOvfCap + i];
            const int dx = ax - cb[3 * j + 0];
            const int dy = ay - cb[3 * j + 1];
            const int dz = az - cb[3 * j + 2];
            const uint32_t d2 = (uint32_t)(dx * dx + dy * dy + dz * dz);
            INSERT5(l0, l1, l2, l3, l4, (d2 << 13) | j);
        }
        groupMerge5_(l0, l1, l2, l3, l4);
        merge5_(g0, g1, g2, g3, g4, l0, l1, l2, l3, l4);
    }
    if (!needFull && (g4 >> 13) > (uint32_t)kDMax) needFull = true;
    if (__any(needFull)) {
        if (needFull) {
            const int* cb = coords_b + (size_t)b * kNb * 3;
            uint32_t u0 = 0xFFFFFFFFu, u1 = u0, u2 = u0, u3 = u0, u4 = u0;
            for (int j = sub; j < kNb; j += 16) {
                const int dx = ax - cb[3 * j + 0];
                const int dy = ay - cb[3 * j + 1];
                const int dz = az - cb[3 * j + 2];
                const uint32_t d2 = (uint32_t)(dx * dx + dy * dy + dz * dz);
                INSERT5(u0, u1, u2, u3, u4, (d2 << 13) | (uint32_t)j);
            }
            groupMerge5_(u0, u1, u2, u3, u4);
            g0 = u0; g1 = u1; g2 = u2; g3 = u3; g4 = u4;
        }
    }

    // ---- weights + gather: lane = 4 channels (float4) ----
    const float* fb = feat_b + (size_t)b * kNb * kC;
    const uint32_t keys[5] = {g0, g1, g2, g3, g4};
    float4 acc = float4{0.f, 0.f, 0.f, 0.f};
    #pragma unroll
    for (int t = 0; t < 5; ++t) {
        const uint32_t key = keys[t];
        const int j = (int)(key & 8191u);
        const float dist = sqrtf((float)(key >> 13)) * (1.0f / 32.0f);
        const float w = 0.5f - fminf(dist, 0.5f);
        const float4 v = *reinterpret_cast<const float4*>(
                             fb + (size_t)j * kC + sub * 4);
        acc.x += w * v.x; acc.y += w * v.y; acc.z += w * v.z; acc.w += w * v.w;
    }

    const size_t orow = ((size_t)b * kNa + row) * (2 * kC);
    *reinterpret_cast<float4*>(out + orow + sub * 4) = fa;
    *reinterpret_cast<float4*>(out + orow + kC + sub * 4) = acc;
}

// ---------------- brute kernel (fallback if ws too small) ----------------

__global__ __launch_bounds__(512, 8)
void dist_match_brute(const int* __restrict__ coords_a,
                      const int* __restrict__ coords_b,
                      const float* __restrict__ feat_a,
                      const float* __restrict__ feat_b,
                      float* __restrict__ out)
{
    __shared__ int spack[kNb];
    const int b = blockIdx.x >> 10;
    const int rowBase = (blockIdx.x & 1023) * 8;
    const int tid = threadIdx.x;
    const int lane = tid & 63;
    const int wave = tid >> 6;

    const int* cb = coords_b + (size_t)b * kNb * 3;
    for (int j = tid; j < kNb; j += 512) {
        spack[j] = cb[3 * j + 0] | (cb[3 * j + 1] << 8) | (cb[3 * j + 2] << 16);
    }
    __syncthreads();

    const int row = rowBase + wave;
    const int* ca = coords_a + ((size_t)b * kNa + row) * 3;
    const int ax = ca[0], ay = ca[1], az = ca[2];
    const int a2 = ax * ax + ay * ay + az * az;
    const int paneg2 = ((-2 * ax) & 255) | (((-2 * ay) & 255) << 8)
                     | (((-2 * az) & 255) << 16);

    uint32_t t0 = 0xFFFFFFFFu, t1 = t0, t2 = t0, t3 = t0, t4 = t0;
    for (int k = 0; k < kNb / 256; ++k) {
        const int baseI = k * 256 + lane * 4;
        const int4 p4 = *reinterpret_cast<const int4*>(spack + baseI);
        const int ps[4] = {p4.x, p4.y, p4.z, p4.w};
        #pragma unroll
        for (int u = 0; u < 4; ++u) {
            const int p = ps[u];
            const int dot1 = __builtin_amdgcn_sdot4(paneg2, p, a2, false);
            const int d2 = __builtin_amdgcn_sdot4(p, p, dot1, false);
            const uint32_t key = ((uint32_t)d2 << 13) | (uint32_t)(baseI + u);
            INSERT5(t0, t1, t2, t3, t4, key);
        }
    }
    waveMerge5_(t0, t1, t2, t3, t4);
    const float* fb = feat_b + (size_t)b * kNb * kC;
    const uint32_t keys[5] = {t0, t1, t2, t3, t4};
    float acc = 0.0f;
    #pragma unroll
    for (int t = 0; t < 5; ++t) {
        const uint32_t key = keys[t];
        const int j = (int)(key & 8191u);
        const float dist = sqrtf((float)(key >> 13)) * (1.0f / 32.0f);
        const float w = 0.5f - fminf(dist, 0.5f);
        acc += w * fb[(size_t)j * kC + lane];
    }
    const size_t orow = ((size_t)b * kNa + row) * (2 * kC);
    out[orow + lane] = feat_a[((size_t)b * kNa + row) * kC + lane];
    out[orow + kC + lane] = acc;
}

extern "C" void kernel_launch(void* const* d_in, const int* in_sizes, int n_in,
                              void* d_out, int out_size, void* d_ws, size_t ws_size,
                              hipStream_t stream) {
    const int* coords_a = (const int*)d_in[0];
    const int* coords_b = (const int*)d_in[1];
    const float* feat_a = (const float*)d_in[2];
    const float* feat_b = (const float*)d_in[3];
    float* out = (float*)d_out;

    if (ws_size < kWsBytes) {
        dist_match_brute<<<kB * 1024, 512, 0, stream>>>(coords_a, coords_b,
                                                        feat_a, feat_b, out);
        return;
    }

    uint32_t* ws32 = (uint32_t*)d_ws;
    uint32_t* cnt    = ws32 + kCntOff;
    uint32_t* ovfCnt = ws32 + kOvfCntOff;
    uint32_t* ovfIdx = ws32 + kOvfIdxOff;
    uint16_t* slot16 = (uint16_t*)(ws32 + kSlot16Off);
    uint32_t* slotHi = ws32 + kSlotHiOff;

    k_clear<<<kClrBlocks, 256, 0, stream>>>((uint4*)d_ws);
    k_scatter<<<kB * kNb / 256, 256, 0, stream>>>(coords_b, cnt, slot16, slotHi,
                                                  ovfCnt, ovfIdx);
    dist_match_bucket<<<kB * 256, 512, 0, stream>>>(coords_a, coords_b,
                                                    feat_a, feat_b,
                                                    cnt, slot16, slotHi,
                                                    ovfCnt, ovfIdx, out);
}